// Round 5
// baseline (547.297 us; speedup 1.0000x reference)
//
#include <hip/hip_runtime.h>
#include <hip/hip_bf16.h>

// ---------------------------------------------------------------------------
// MambaBlock: delta/dbar via bf16 MFMA GEMM1 (fast-softplus+row-mean epilogue),
// Bt/Ct via skinny MFMA GEMM, fused chunk-parallel linear scan (scan+stitch+
// fixup in one kernel), out = diag(s)*(x@Wo)+bo via bf16 MFMA GEMM2.
// B=8 T=4096 D=1024 N=16, M=B*T=32768.
//
// R3: 256x256-tile 8-wave GEMM core, 4-deep LDS ring + counted vmcnt(8),
//     sigma-swizzled conflict-free LDS subtiles. (88us gemm1, MfmaUtil 32%)
// R4: (a) 2-phase K-tile schedule: per tile {ds_read G1 | stage A-half |
//     lgkmcnt(0)+sched_barrier | setprio 16 MFMA | barrier | ds_read G2 |
//     stage B-half | 16 MFMA} - converts serial sum (reads+MFMA) into
//     cross-wave overlap (T3/T5 chain). vmcnt ring invariant unchanged.
//     (b) fused scan kernel: pass1 chunk-scan (h_end,P) -> LDS stitch ->
//     pass2 exact rescan with correct h0; 3 kernels -> 1, no per-row
//     intermediate buffers.
// R5: identical resubmit of R4 (previous round died on container acquisition,
//     not on the kernel — audited for hangs: barriers uniform, ring hazard
//     clean, vmcnt ledger consistent).
// ---------------------------------------------------------------------------

typedef __bf16 bfx4 __attribute__((ext_vector_type(4)));
typedef __bf16 bfx8 __attribute__((ext_vector_type(8)));
typedef float  f32x4 __attribute__((ext_vector_type(4)));

#define M_ROWS 32768
#define DDIM   1024
#define NSTATE 16
#define TLEN   4096
#define BATCH  8

#define BK     32
#define KT     (DDIM / BK)        // 32 K-tiles
#define TILEE  16384              // elements per ring buffer (A 8192 + B 8192)

// ---------------- prep: weight transposes + casts --------------------------
__global__ __launch_bounds__(256) void transpose_w_kernel(
    const float* __restrict__ Wd, const float* __restrict__ Wo,
    __bf16* __restrict__ WdT, __bf16* __restrict__ WoT)
{
    __shared__ float tile[32][33];
    const int bid = blockIdx.x;                 // 0..2047
    const float* src = (bid < 1024) ? Wd : Wo;
    __bf16* dst = (bid < 1024) ? WdT : WoT;
    const int t = bid & 1023;
    const int tr = t >> 5, tc = t & 31;
    const int tx = threadIdx.x & 31, ty = threadIdx.x >> 5;  // ty 0..7
#pragma unroll
    for (int i = 0; i < 4; ++i) {
        int r = ty + i * 8;
        tile[r][tx] = src[(size_t)(tr * 32 + r) * 1024 + tc * 32 + tx];
    }
    __syncthreads();
#pragma unroll
    for (int i = 0; i < 4; ++i) {
        int r = ty + i * 8;
        dst[(size_t)(tc * 32 + r) * 1024 + tr * 32 + tx] = (__bf16)tile[tx][r];
    }
}

// Wbc: [32][1024] bf16 ; rows 0..15 = Wb^T, rows 16..31 = Wc^T
__global__ __launch_bounds__(256) void wbc_kernel(
    const float* __restrict__ Wb, const float* __restrict__ Wc,
    __bf16* __restrict__ Wbc)
{
    int idx = blockIdx.x * 256 + threadIdx.x;   // 0..32767
    int n2 = idx >> 10, k = idx & 1023;
    float v = (n2 < 16) ? Wb[k * 16 + n2] : Wc[k * 16 + (n2 - 16)];
    Wbc[idx] = (__bf16)v;
}

__global__ __launch_bounds__(256) void sA_kernel(const float* __restrict__ A,
                                                 float* __restrict__ sA)
{
    __shared__ float red[256];
    int tid = threadIdx.x;
    int n = tid & 15, part = tid >> 4;
    float sum = 0.f;
    for (int k = part * 64; k < part * 64 + 64; ++k) sum += A[k * 16 + n];
    red[tid] = sum;
    __syncthreads();
    if (tid < 16) {
        float tot = 0.f;
        for (int p = 0; p < 16; ++p) tot += red[p * 16 + tid];
        sA[tid] = 1.f / (1.f + expf(-tot * (1.f / 1024.f)));
    }
}

// ------------------ cast x -> bf16 (pure streaming) ------------------------
__global__ __launch_bounds__(256) void cast_kernel(const float* __restrict__ x,
                                                   __bf16* __restrict__ xb)
{
    size_t i = ((size_t)blockIdx.x * 256 + threadIdx.x) * 8;
    const float4* xg = (const float4*)(x + i);
    float4 v0 = xg[0], v1 = xg[1];
    bfx8 o;
    o[0] = (__bf16)v0.x; o[1] = (__bf16)v0.y; o[2] = (__bf16)v0.z; o[3] = (__bf16)v0.w;
    o[4] = (__bf16)v1.x; o[5] = (__bf16)v1.y; o[6] = (__bf16)v1.z; o[7] = (__bf16)v1.w;
    *(bfx8*)(xb + i) = o;
}

// ---------------- Bt/Ct: skinny MFMA GEMM, no LDS --------------------------
__global__ __launch_bounds__(256) void btct_kernel(
    const __bf16* __restrict__ xb, const __bf16* __restrict__ Wbc,
    const float* __restrict__ bb, const float* __restrict__ bc,
    float* __restrict__ Bt, float* __restrict__ Ct)
{
    const int wid = blockIdx.x * 4 + (threadIdx.x >> 6);  // 0..2047
    const int lane = threadIdx.x & 63;
    const int quad = lane >> 4, l15 = lane & 15;
    const int mbase = wid * 16;
    const __bf16* ga = xb + (size_t)(mbase + l15) * 1024 + quad * 8;
    const __bf16* gb = Wbc + (size_t)l15 * 1024 + quad * 8;
    const __bf16* gc = Wbc + (size_t)(16 + l15) * 1024 + quad * 8;
    f32x4 accB = {0.f, 0.f, 0.f, 0.f};
    f32x4 accC = {0.f, 0.f, 0.f, 0.f};
#pragma unroll 4
    for (int k = 0; k < 1024; k += 32) {
        bfx8 a = *(const bfx8*)ga;  ga += 32;
        bfx8 b = *(const bfx8*)gb;  gb += 32;
        bfx8 c = *(const bfx8*)gc;  gc += 32;
        accB = __builtin_amdgcn_mfma_f32_16x16x32_bf16(a, b, accB, 0, 0, 0);
        accC = __builtin_amdgcn_mfma_f32_16x16x32_bf16(a, c, accC, 0, 0, 0);
    }
    // C/D layout: col = lane&15, row = quad*4 + r
#pragma unroll
    for (int r = 0; r < 4; ++r) {
        int row = mbase + quad * 4 + r;
        Bt[row * 16 + l15] = accB[r] + bb[l15];
        Ct[row * 16 + l15] = accC[r] + bc[l15];
    }
}

// ------------------------- 256x256 MFMA GEMM core --------------------------
__device__ __forceinline__ void gload16(const void* g, void* l)
{
    __builtin_amdgcn_global_load_lds((__attribute__((address_space(1))) void*)g,
                                     (__attribute__((address_space(3))) void*)l,
                                     16, 0, 0);
}

// XCD-aware tile swizzle for 512 blocks (128 mtiles x 4 ntiles). Bijective.
__device__ __forceinline__ void tile_swizzle256(int L, int& mtile, int& ntile)
{
    int xcd = L & 7;
    int s = L >> 3;           // 0..63
    mtile = xcd * 16 + (s >> 2);
    ntile = s & 3;
}

// LDS layout per 256x32 bf16 operand tile (16KB = 16 subtiles of 1KB):
//   sigma: kc' = kc ^ (((row&15)>>1)&3) within each 64B row (within-line
//   permutation only -> staging groups stay inside one 64B global line).
// Fragment read: any 8 consecutive lanes hit 8 distinct 16B slots -> 0 confl.
// Ring: 4 buffers x 32KB = 128KB; stage t+3 while computing t; vmcnt(8)/tile.
__device__ __forceinline__ void stage_tile(const __bf16* pA0, const __bf16* pA1,
                                           const __bf16* pB0, const __bf16* pB1,
                                           __bf16* lbase, int tid, int t)
{
    const size_t ko = (size_t)t * BK;
    __bf16* ba = lbase;
    __bf16* bb2 = lbase + 8192;
    gload16(pA0 + ko, ba + tid * 8);
    gload16(pA1 + ko, ba + 4096 + tid * 8);
    gload16(pB0 + ko, bb2 + tid * 8);
    gload16(pB1 + ko, bb2 + 4096 + tid * 8);
}

__device__ __forceinline__ void gemm_core256(const __bf16* __restrict__ Abuf,
                                             const __bf16* __restrict__ Bbuf,
                                             __bf16* lds,
                                             int mbase, int nbase,
                                             f32x4 acc[8][4])
{
    const int tid = threadIdx.x;
    const int lane = tid & 63;
    const int w = tid >> 6;
    const int quad = lane >> 4, l15 = lane & 15;
    const int wm = w >> 2, wn = w & 3;        // 2 x 4 wave grid

    // staging source addressing (per thread)
    const int row0 = ((tid >> 6) << 4) + ((tid >> 2) & 15);
    const int kc   = (tid & 3) ^ ((tid >> 3) & 3);
    const __bf16* pA0 = Abuf + (size_t)(mbase + row0) * DDIM + kc * 8;
    const __bf16* pA1 = pA0 + (size_t)128 * DDIM;
    const __bf16* pB0 = Bbuf + (size_t)(nbase + row0) * DDIM + kc * 8;
    const __bf16* pB1 = pB0 + (size_t)128 * DDIM;

    // fragment read offsets (sigma-swizzled slot within subtile)
    const int vsw  = l15 * 4 + (quad ^ ((l15 >> 1) & 3));
    const int aoff = wm * 8 * 512 + vsw * 8;
    const int boff = wn * 4 * 512 + vsw * 8;

    // prologue: stage tiles 0,1,2 (12 loads in flight)
    stage_tile(pA0, pA1, pB0, pB1, lds + 0 * TILEE, tid, 0);
    stage_tile(pA0, pA1, pB0, pB1, lds + 1 * TILEE, tid, 1);
    stage_tile(pA0, pA1, pB0, pB1, lds + 2 * TILEE, tid, 2);

#pragma unroll 1
    for (int t = 0; t < KT; ++t) {
        // tile t's 4 loads are the oldest outstanding; up to 8 newer remain
        if (t < KT - 2)       asm volatile("s_waitcnt vmcnt(8)" ::: "memory");
        else if (t == KT - 2) asm volatile("s_waitcnt vmcnt(4)" ::: "memory");
        else                  asm volatile("s_waitcnt vmcnt(0)" ::: "memory");
        __builtin_amdgcn_s_barrier();
        __builtin_amdgcn_sched_barrier(0);

        const __bf16* Al = lds + (t & 3) * TILEE;
        const __bf16* Bl = Al + 8192;
        const size_t ko3 = (size_t)(t + 3) * BK;
        __bf16* lb3 = lds + ((t + 3) & 3) * TILEE;

        // -------- phase 1: i=0..3 x all j ; stage A-half of tile t+3
        bfx8 bfr[4], af[4];
#pragma unroll
        for (int j = 0; j < 4; ++j) bfr[j] = *(const bfx8*)(Bl + boff + j * 512);
#pragma unroll
        for (int i = 0; i < 4; ++i) af[i]  = *(const bfx8*)(Al + aoff + i * 512);
        if (t < KT - 3) {
            gload16(pA0 + ko3, lb3 + tid * 8);
            gload16(pA1 + ko3, lb3 + 4096 + tid * 8);
        }
        asm volatile("s_waitcnt lgkmcnt(0)" ::: "memory");
        __builtin_amdgcn_sched_barrier(0);
        __builtin_amdgcn_s_setprio(1);
#pragma unroll
        for (int i = 0; i < 4; ++i)
#pragma unroll
            for (int j = 0; j < 4; ++j)
                acc[i][j] = __builtin_amdgcn_mfma_f32_16x16x32_bf16(
                    af[i], bfr[j], acc[i][j], 0, 0, 0);
        __builtin_amdgcn_s_setprio(0);
        __builtin_amdgcn_s_barrier();

        // -------- phase 2: i=4..7 x all j ; stage B-half of tile t+3
#pragma unroll
        for (int i = 0; i < 4; ++i) af[i] = *(const bfx8*)(Al + aoff + (4 + i) * 512);
        if (t < KT - 3) {
            gload16(pB0 + ko3, lb3 + 8192 + tid * 8);
            gload16(pB1 + ko3, lb3 + 8192 + 4096 + tid * 8);
        }
        asm volatile("s_waitcnt lgkmcnt(0)" ::: "memory");
        __builtin_amdgcn_sched_barrier(0);
        __builtin_amdgcn_s_setprio(1);
#pragma unroll
        for (int i = 0; i < 4; ++i)
#pragma unroll
            for (int j = 0; j < 4; ++j)
                acc[4 + i][j] = __builtin_amdgcn_mfma_f32_16x16x32_bf16(
                    af[i], bfr[j], acc[4 + i][j], 0, 0, 0);
        __builtin_amdgcn_s_setprio(0);
    }
}

// GEMM1: z = x@Wd + bd ; dbar[row] += mean_cols softplus(z)
__global__ __launch_bounds__(512, 2) void gemm1_kernel(
    const __bf16* __restrict__ xb, const __bf16* __restrict__ WdT,
    const float* __restrict__ bd, float* __restrict__ dbar)
{
    __shared__ __bf16 lds[4 * TILEE];   // 128 KB
    f32x4 acc[8][4];
    f32x4 z4 = {0.f, 0.f, 0.f, 0.f};
#pragma unroll
    for (int i = 0; i < 8; ++i)
#pragma unroll
        for (int j = 0; j < 4; ++j) acc[i][j] = z4;

    int mtile, ntile;
    tile_swizzle256(blockIdx.x, mtile, ntile);
    const int mbase = mtile * 256;
    const int nbase = ntile * 256;
    gemm_core256(xb, WdT, lds, mbase, nbase, acc);

    const int lane = threadIdx.x & 63;
    const int w = threadIdx.x >> 6;
    const int quad = lane >> 4, l15 = lane & 15;
    const int wm = w >> 2, wn = w & 3;
    const float invD = 1.0f / 1024.0f;
#pragma unroll
    for (int i = 0; i < 8; ++i) {
#pragma unroll
        for (int r = 0; r < 4; ++r) {
            float sp = 0.f;
#pragma unroll
            for (int j = 0; j < 4; ++j) {
                int col = nbase + wn * 64 + j * 16 + l15;
                float z = acc[i][j][r] + bd[col];
                sp += fmaxf(z, 0.f) + __logf(1.f + __expf(-fabsf(z)));
            }
#pragma unroll
            for (int off = 1; off < 16; off <<= 1) sp += __shfl_xor(sp, off, 16);
            if (l15 == 0) {
                int row = mbase + wm * 128 + i * 16 + quad * 4 + r;
                atomicAdd(&dbar[row], sp * invD);
            }
        }
    }
}

// GEMM2: out[row][col] = s[row]*(x@Wo)[row][col] + bo[col]
__global__ __launch_bounds__(512, 2) void gemm2_kernel(
    const __bf16* __restrict__ xb, const __bf16* __restrict__ WoT,
    const float* __restrict__ srow, const float* __restrict__ bo,
    float* __restrict__ out)
{
    __shared__ __bf16 lds[4 * TILEE];   // 128 KB
    f32x4 acc[8][4];
    f32x4 z4 = {0.f, 0.f, 0.f, 0.f};
#pragma unroll
    for (int i = 0; i < 8; ++i)
#pragma unroll
        for (int j = 0; j < 4; ++j) acc[i][j] = z4;

    int mtile, ntile;
    tile_swizzle256(blockIdx.x, mtile, ntile);
    const int mbase = mtile * 256;
    const int nbase = ntile * 256;
    gemm_core256(xb, WoT, lds, mbase, nbase, acc);

    const int lane = threadIdx.x & 63;
    const int w = threadIdx.x >> 6;
    const int quad = lane >> 4, l15 = lane & 15;
    const int wm = w >> 2, wn = w & 3;
#pragma unroll
    for (int i = 0; i < 8; ++i) {
        int row0 = mbase + wm * 128 + i * 16 + quad * 4;
#pragma unroll
        for (int r = 0; r < 4; ++r) {
            float sv = srow[row0 + r];
#pragma unroll
            for (int j = 0; j < 4; ++j) {
                int col = nbase + wn * 64 + j * 16 + l15;
                out[(size_t)(row0 + r) * 1024 + col] = sv * acc[i][j][r] + bo[col];
            }
        }
    }
}

// --------------------- fused chunk-parallel linear scan --------------------
// h_t = (1-dbar_t) h_{t-1} + dbar_t * Bt_t * sA ;  s_t = <h_t, Ct_t>
// One block per batch (8 blocks, 256 thr = 16 chunk-groups x 16 lanes).
// Pass 1: each group scans its 256-step chunk from h0=0 -> (Hend, P) in LDS.
// Stitch: 16 threads serially combine chunks -> per-chunk true h0.
// Pass 2: exact rescan from true h0, emit s_t. All data L2-resident (4.4MB).
__global__ __launch_bounds__(256) void scan_fused_kernel(
    const float* __restrict__ dbar, const float* __restrict__ Bt,
    const float* __restrict__ Ct, const float* __restrict__ sA,
    float* __restrict__ sbuf)
{
    __shared__ float Hend_s[16][16];
    __shared__ float P_s[16];
    __shared__ float H0_s[16][16];
    const int tid = threadIdx.x;
    const int g = tid >> 4, n = tid & 15;
    const int b = blockIdx.x;
    const float sAn = sA[n];
    const int row0 = b * TLEN + g * 256;

    float h = 0.f, p = 1.f;
#pragma unroll 4
    for (int t = 0; t < 256; ++t) {
        int row = row0 + t;
        float d = dbar[row];
        float btv = Bt[row * 16 + n];
        float a = 1.f - d;
        h = h * a + d * sAn * btv;
        p *= a;
    }
    Hend_s[g][n] = h;
    if (n == 0) P_s[g] = p;
    __syncthreads();
    if (tid < 16) {   // tid indexes n; serial over 16 chunks
        float h0 = 0.f;
#pragma unroll
        for (int c = 0; c < 16; ++c) {
            H0_s[c][tid] = h0;
            h0 = P_s[c] * h0 + Hend_s[c][tid];
        }
    }
    __syncthreads();
    h = H0_s[g][n];
#pragma unroll 4
    for (int t = 0; t < 256; ++t) {
        int row = row0 + t;
        float d = dbar[row];
        float btv = Bt[row * 16 + n];
        float ctv = Ct[row * 16 + n];
        float a = 1.f - d;
        h = h * a + d * sAn * btv;
        float prod = h * ctv;
#pragma unroll
        for (int off = 1; off < 16; off <<= 1) prod += __shfl_xor(prod, off, 16);
        if (n == 0) sbuf[row] = prod;
    }
}

// ---------------------------------------------------------------------------
extern "C" void kernel_launch(void* const* d_in, const int* in_sizes, int n_in,
                              void* d_out, int out_size, void* d_ws, size_t ws_size,
                              hipStream_t stream)
{
    const float* x  = (const float*)d_in[0];
    const float* Wd = (const float*)d_in[1];
    const float* bd = (const float*)d_in[2];
    const float* Wb = (const float*)d_in[3];
    const float* bb = (const float*)d_in[4];
    const float* Wc = (const float*)d_in[5];
    const float* bc = (const float*)d_in[6];
    const float* Wo = (const float*)d_in[7];
    const float* bo = (const float*)d_in[8];
    const float* A  = (const float*)d_in[9];
    float* out = (float*)d_out;

    char* base = (char*)d_ws;
    size_t off = 0;
    auto alloc = [&](size_t bytes) -> void* {
        void* p = base + off;
        off = (off + bytes + 255) & ~(size_t)255;
        return p;
    };
    __bf16* xb   = (__bf16*)alloc((size_t)M_ROWS * DDIM * 2);  // 67 MB
    __bf16* WdT  = (__bf16*)alloc((size_t)DDIM * DDIM * 2);    // 2 MB
    __bf16* WoT  = (__bf16*)alloc((size_t)DDIM * DDIM * 2);    // 2 MB
    __bf16* Wbc  = (__bf16*)alloc(32 * 1024 * 2);              // 64 KB
    float* sAbuf = (float*)alloc(64);
    float* dbar  = (float*)alloc(M_ROWS * 4);
    float* Bt    = (float*)alloc((size_t)M_ROWS * 16 * 4);     // 2 MB
    float* Ct    = (float*)alloc((size_t)M_ROWS * 16 * 4);     // 2 MB
    float* sbuf  = (float*)alloc(M_ROWS * 4);

    transpose_w_kernel<<<2048, 256, 0, stream>>>(Wd, Wo, WdT, WoT);
    wbc_kernel<<<128, 256, 0, stream>>>(Wb, Wc, Wbc);
    sA_kernel<<<1, 256, 0, stream>>>(A, sAbuf);
    cast_kernel<<<M_ROWS * DDIM / 8 / 256, 256, 0, stream>>>(x, xb);
    (void)hipMemsetAsync(dbar, 0, M_ROWS * 4, stream);
    btct_kernel<<<512, 256, 0, stream>>>(xb, Wbc, bb, bc, Bt, Ct);
    gemm1_kernel<<<512, 512, 0, stream>>>(xb, WdT, bd, dbar);
    scan_fused_kernel<<<BATCH, 256, 0, stream>>>(dbar, Bt, Ct, sAbuf, sbuf);
    gemm2_kernel<<<512, 512, 0, stream>>>(xb, WoT, sbuf, bo, out);
}

// Round 6
// 461.232 us; speedup vs baseline: 1.1866x; 1.1866x over previous
//
#include <hip/hip_runtime.h>
#include <hip/hip_bf16.h>

// ---------------------------------------------------------------------------
// MambaBlock: delta/dbar via bf16 MFMA GEMM1 (fast-softplus+row-mean epilogue),
// Bt/Ct via skinny MFMA GEMM, chunk-parallel linear scan (3-kernel trio),
// out = diag(s)*(x@Wo)+bo via bf16 MFMA GEMM2 (row-scale epilogue).
// B=8 T=4096 D=1024 N=16, M=B*T=32768.
//
// R3: 256x256-tile 8-wave GEMM core, 4-deep LDS ring + counted vmcnt(8),
//     sigma-swizzled conflict-free LDS subtiles. (88us gemm1, MfmaUtil 32%)
// R5: 2-phase mid-barrier gemm = NEUTRAL; fused scan (8 blocks) = -88us
//     REGRESSION (0.34% occupancy). Lesson: scan needs 1024-way parallelism.
// R6: (a) scan reverted to proven trio (CHUNK=32, 1024 chains).
//     (b) gemm: drop mid-tile barrier; counted lgkmcnt(4)/(0) split so the
//     last 4 ds_reads + B-half staging ride under the first 16-MFMA cluster.
//     Inter-wave sync identical to verified R3 (1 barrier + vmcnt(8)/tile).
// ---------------------------------------------------------------------------

typedef __bf16 bfx4 __attribute__((ext_vector_type(4)));
typedef __bf16 bfx8 __attribute__((ext_vector_type(8)));
typedef float  f32x4 __attribute__((ext_vector_type(4)));

#define M_ROWS 32768
#define DDIM   1024
#define NSTATE 16
#define TLEN   4096
#define BATCH  8
#define CHUNK  32
#define NCHUNK 128   // TLEN / CHUNK
#define NGROUP (BATCH * NCHUNK)   // 1024 scan chains

#define BK     32
#define KT     (DDIM / BK)        // 32 K-tiles
#define TILEE  16384              // elements per ring buffer (A 8192 + B 8192)

// ---------------- prep: weight transposes + casts --------------------------
__global__ __launch_bounds__(256) void transpose_w_kernel(
    const float* __restrict__ Wd, const float* __restrict__ Wo,
    __bf16* __restrict__ WdT, __bf16* __restrict__ WoT)
{
    __shared__ float tile[32][33];
    const int bid = blockIdx.x;                 // 0..2047
    const float* src = (bid < 1024) ? Wd : Wo;
    __bf16* dst = (bid < 1024) ? WdT : WoT;
    const int t = bid & 1023;
    const int tr = t >> 5, tc = t & 31;
    const int tx = threadIdx.x & 31, ty = threadIdx.x >> 5;  // ty 0..7
#pragma unroll
    for (int i = 0; i < 4; ++i) {
        int r = ty + i * 8;
        tile[r][tx] = src[(size_t)(tr * 32 + r) * 1024 + tc * 32 + tx];
    }
    __syncthreads();
#pragma unroll
    for (int i = 0; i < 4; ++i) {
        int r = ty + i * 8;
        dst[(size_t)(tc * 32 + r) * 1024 + tr * 32 + tx] = (__bf16)tile[tx][r];
    }
}

// Wbc: [32][1024] bf16 ; rows 0..15 = Wb^T, rows 16..31 = Wc^T
__global__ __launch_bounds__(256) void wbc_kernel(
    const float* __restrict__ Wb, const float* __restrict__ Wc,
    __bf16* __restrict__ Wbc)
{
    int idx = blockIdx.x * 256 + threadIdx.x;   // 0..32767
    int n2 = idx >> 10, k = idx & 1023;
    float v = (n2 < 16) ? Wb[k * 16 + n2] : Wc[k * 16 + (n2 - 16)];
    Wbc[idx] = (__bf16)v;
}

__global__ __launch_bounds__(256) void sA_kernel(const float* __restrict__ A,
                                                 float* __restrict__ sA)
{
    __shared__ float red[256];
    int tid = threadIdx.x;
    int n = tid & 15, part = tid >> 4;
    float sum = 0.f;
    for (int k = part * 64; k < part * 64 + 64; ++k) sum += A[k * 16 + n];
    red[tid] = sum;
    __syncthreads();
    if (tid < 16) {
        float tot = 0.f;
        for (int p = 0; p < 16; ++p) tot += red[p * 16 + tid];
        sA[tid] = 1.f / (1.f + expf(-tot * (1.f / 1024.f)));
    }
}

// ------------------ cast x -> bf16 (pure streaming) ------------------------
__global__ __launch_bounds__(256) void cast_kernel(const float* __restrict__ x,
                                                   __bf16* __restrict__ xb)
{
    size_t i = ((size_t)blockIdx.x * 256 + threadIdx.x) * 8;
    const float4* xg = (const float4*)(x + i);
    float4 v0 = xg[0], v1 = xg[1];
    bfx8 o;
    o[0] = (__bf16)v0.x; o[1] = (__bf16)v0.y; o[2] = (__bf16)v0.z; o[3] = (__bf16)v0.w;
    o[4] = (__bf16)v1.x; o[5] = (__bf16)v1.y; o[6] = (__bf16)v1.z; o[7] = (__bf16)v1.w;
    *(bfx8*)(xb + i) = o;
}

// ---------------- Bt/Ct: skinny MFMA GEMM, no LDS --------------------------
__global__ __launch_bounds__(256) void btct_kernel(
    const __bf16* __restrict__ xb, const __bf16* __restrict__ Wbc,
    const float* __restrict__ bb, const float* __restrict__ bc,
    float* __restrict__ Bt, float* __restrict__ Ct)
{
    const int wid = blockIdx.x * 4 + (threadIdx.x >> 6);  // 0..2047
    const int lane = threadIdx.x & 63;
    const int quad = lane >> 4, l15 = lane & 15;
    const int mbase = wid * 16;
    const __bf16* ga = xb + (size_t)(mbase + l15) * 1024 + quad * 8;
    const __bf16* gb = Wbc + (size_t)l15 * 1024 + quad * 8;
    const __bf16* gc = Wbc + (size_t)(16 + l15) * 1024 + quad * 8;
    f32x4 accB = {0.f, 0.f, 0.f, 0.f};
    f32x4 accC = {0.f, 0.f, 0.f, 0.f};
#pragma unroll 4
    for (int k = 0; k < 1024; k += 32) {
        bfx8 a = *(const bfx8*)ga;  ga += 32;
        bfx8 b = *(const bfx8*)gb;  gb += 32;
        bfx8 c = *(const bfx8*)gc;  gc += 32;
        accB = __builtin_amdgcn_mfma_f32_16x16x32_bf16(a, b, accB, 0, 0, 0);
        accC = __builtin_amdgcn_mfma_f32_16x16x32_bf16(a, c, accC, 0, 0, 0);
    }
    // C/D layout: col = lane&15, row = quad*4 + r
#pragma unroll
    for (int r = 0; r < 4; ++r) {
        int row = mbase + quad * 4 + r;
        Bt[row * 16 + l15] = accB[r] + bb[l15];
        Ct[row * 16 + l15] = accC[r] + bc[l15];
    }
}

// ------------------------- 256x256 MFMA GEMM core --------------------------
__device__ __forceinline__ void gload16(const void* g, void* l)
{
    __builtin_amdgcn_global_load_lds((__attribute__((address_space(1))) void*)g,
                                     (__attribute__((address_space(3))) void*)l,
                                     16, 0, 0);
}

// XCD-aware tile swizzle for 512 blocks (128 mtiles x 4 ntiles). Bijective.
__device__ __forceinline__ void tile_swizzle256(int L, int& mtile, int& ntile)
{
    int xcd = L & 7;
    int s = L >> 3;           // 0..63
    mtile = xcd * 16 + (s >> 2);
    ntile = s & 3;
}

// LDS layout per 256x32 bf16 operand tile (16KB = 16 subtiles of 1KB):
//   sigma: kc' = kc ^ (((row&15)>>1)&3) within each 64B row (within-line
//   permutation only -> staging groups stay inside one 64B global line).
// Fragment read: any 8 consecutive lanes hit 8 distinct 16B slots -> 0 confl.
// Ring: 4 buffers x 32KB = 128KB; stage t+3 while computing t; vmcnt(8)/tile.
__device__ __forceinline__ void stage_tile(const __bf16* pA0, const __bf16* pA1,
                                           const __bf16* pB0, const __bf16* pB1,
                                           __bf16* lbase, int tid, int t)
{
    const size_t ko = (size_t)t * BK;
    __bf16* ba = lbase;
    __bf16* bb2 = lbase + 8192;
    gload16(pA0 + ko, ba + tid * 8);
    gload16(pA1 + ko, ba + 4096 + tid * 8);
    gload16(pB0 + ko, bb2 + tid * 8);
    gload16(pB1 + ko, bb2 + 4096 + tid * 8);
}

__device__ __forceinline__ void gemm_core256(const __bf16* __restrict__ Abuf,
                                             const __bf16* __restrict__ Bbuf,
                                             __bf16* lds,
                                             int mbase, int nbase,
                                             f32x4 acc[8][4])
{
    const int tid = threadIdx.x;
    const int lane = tid & 63;
    const int w = tid >> 6;
    const int quad = lane >> 4, l15 = lane & 15;
    const int wm = w >> 2, wn = w & 3;        // 2 x 4 wave grid

    // staging source addressing (per thread)
    const int row0 = ((tid >> 6) << 4) + ((tid >> 2) & 15);
    const int kc   = (tid & 3) ^ ((tid >> 3) & 3);
    const __bf16* pA0 = Abuf + (size_t)(mbase + row0) * DDIM + kc * 8;
    const __bf16* pA1 = pA0 + (size_t)128 * DDIM;
    const __bf16* pB0 = Bbuf + (size_t)(nbase + row0) * DDIM + kc * 8;
    const __bf16* pB1 = pB0 + (size_t)128 * DDIM;

    // fragment read offsets (sigma-swizzled slot within subtile)
    const int vsw  = l15 * 4 + (quad ^ ((l15 >> 1) & 3));
    const int aoff = wm * 8 * 512 + vsw * 8;
    const int boff = wn * 4 * 512 + vsw * 8;

    // prologue: stage tiles 0,1,2 (12 loads in flight)
    stage_tile(pA0, pA1, pB0, pB1, lds + 0 * TILEE, tid, 0);
    stage_tile(pA0, pA1, pB0, pB1, lds + 1 * TILEE, tid, 1);
    stage_tile(pA0, pA1, pB0, pB1, lds + 2 * TILEE, tid, 2);

#pragma unroll 1
    for (int t = 0; t < KT; ++t) {
        // tile t's 4 loads are the oldest outstanding; up to 8 newer remain
        if (t < KT - 2)       asm volatile("s_waitcnt vmcnt(8)" ::: "memory");
        else if (t == KT - 2) asm volatile("s_waitcnt vmcnt(4)" ::: "memory");
        else                  asm volatile("s_waitcnt vmcnt(0)" ::: "memory");
        __builtin_amdgcn_s_barrier();
        __builtin_amdgcn_sched_barrier(0);

        const __bf16* Al = lds + (t & 3) * TILEE;
        const __bf16* Bl = Al + 8192;
        const size_t ko3 = (size_t)(t + 3) * BK;
        __bf16* lb3 = lds + ((t + 3) & 3) * TILEE;

        // issue all 12 ds_reads (order: bfr0-3, af0-3, ag0-3) with staging
        // interleaved; counted lgkm waits split the MFMA into two clusters
        // so ag-reads + B-half staging ride under the first cluster.
        bfx8 bfr[4], af[4], ag[4];
#pragma unroll
        for (int j = 0; j < 4; ++j) bfr[j] = *(const bfx8*)(Bl + boff + j * 512);
#pragma unroll
        for (int i = 0; i < 4; ++i) af[i]  = *(const bfx8*)(Al + aoff + i * 512);
        if (t < KT - 3) {
            gload16(pA0 + ko3, lb3 + tid * 8);
            gload16(pA1 + ko3, lb3 + 4096 + tid * 8);
        }
#pragma unroll
        for (int i = 0; i < 4; ++i) ag[i] = *(const bfx8*)(Al + aoff + (4 + i) * 512);
        if (t < KT - 3) {
            gload16(pB0 + ko3, lb3 + 8192 + tid * 8);
            gload16(pB1 + ko3, lb3 + 8192 + 4096 + tid * 8);
        }
        // first 8 ds_reads (bfr, af) complete; ag still in flight
        asm volatile("s_waitcnt lgkmcnt(4)" ::: "memory");
        __builtin_amdgcn_sched_barrier(0);
        __builtin_amdgcn_s_setprio(1);
#pragma unroll
        for (int i = 0; i < 4; ++i)
#pragma unroll
            for (int j = 0; j < 4; ++j)
                acc[i][j] = __builtin_amdgcn_mfma_f32_16x16x32_bf16(
                    af[i], bfr[j], acc[i][j], 0, 0, 0);
        __builtin_amdgcn_s_setprio(0);
        asm volatile("s_waitcnt lgkmcnt(0)" ::: "memory");
        __builtin_amdgcn_sched_barrier(0);
        __builtin_amdgcn_s_setprio(1);
#pragma unroll
        for (int i = 0; i < 4; ++i)
#pragma unroll
            for (int j = 0; j < 4; ++j)
                acc[4 + i][j] = __builtin_amdgcn_mfma_f32_16x16x32_bf16(
                    ag[i], bfr[j], acc[4 + i][j], 0, 0, 0);
        __builtin_amdgcn_s_setprio(0);
    }
}

// GEMM1: z = x@Wd + bd ; dbar[row] += mean_cols softplus(z)
__global__ __launch_bounds__(512, 2) void gemm1_kernel(
    const __bf16* __restrict__ xb, const __bf16* __restrict__ WdT,
    const float* __restrict__ bd, float* __restrict__ dbar)
{
    __shared__ __bf16 lds[4 * TILEE];   // 128 KB
    f32x4 acc[8][4];
    f32x4 z4 = {0.f, 0.f, 0.f, 0.f};
#pragma unroll
    for (int i = 0; i < 8; ++i)
#pragma unroll
        for (int j = 0; j < 4; ++j) acc[i][j] = z4;

    int mtile, ntile;
    tile_swizzle256(blockIdx.x, mtile, ntile);
    const int mbase = mtile * 256;
    const int nbase = ntile * 256;
    gemm_core256(xb, WdT, lds, mbase, nbase, acc);

    const int lane = threadIdx.x & 63;
    const int w = threadIdx.x >> 6;
    const int quad = lane >> 4, l15 = lane & 15;
    const int wm = w >> 2, wn = w & 3;
    const float invD = 1.0f / 1024.0f;
#pragma unroll
    for (int i = 0; i < 8; ++i) {
#pragma unroll
        for (int r = 0; r < 4; ++r) {
            float sp = 0.f;
#pragma unroll
            for (int j = 0; j < 4; ++j) {
                int col = nbase + wn * 64 + j * 16 + l15;
                float z = acc[i][j][r] + bd[col];
                sp += fmaxf(z, 0.f) + __logf(1.f + __expf(-fabsf(z)));
            }
#pragma unroll
            for (int off = 1; off < 16; off <<= 1) sp += __shfl_xor(sp, off, 16);
            if (l15 == 0) {
                int row = mbase + wm * 128 + i * 16 + quad * 4 + r;
                atomicAdd(&dbar[row], sp * invD);
            }
        }
    }
}

// GEMM2: out[row][col] = s[row]*(x@Wo)[row][col] + bo[col]
__global__ __launch_bounds__(512, 2) void gemm2_kernel(
    const __bf16* __restrict__ xb, const __bf16* __restrict__ WoT,
    const float* __restrict__ srow, const float* __restrict__ bo,
    float* __restrict__ out)
{
    __shared__ __bf16 lds[4 * TILEE];   // 128 KB
    f32x4 acc[8][4];
    f32x4 z4 = {0.f, 0.f, 0.f, 0.f};
#pragma unroll
    for (int i = 0; i < 8; ++i)
#pragma unroll
        for (int j = 0; j < 4; ++j) acc[i][j] = z4;

    int mtile, ntile;
    tile_swizzle256(blockIdx.x, mtile, ntile);
    const int mbase = mtile * 256;
    const int nbase = ntile * 256;
    gemm_core256(xb, WoT, lds, mbase, nbase, acc);

    const int lane = threadIdx.x & 63;
    const int w = threadIdx.x >> 6;
    const int quad = lane >> 4, l15 = lane & 15;
    const int wm = w >> 2, wn = w & 3;
#pragma unroll
    for (int i = 0; i < 8; ++i) {
        int row0 = mbase + wm * 128 + i * 16 + quad * 4;
#pragma unroll
        for (int r = 0; r < 4; ++r) {
            float sv = srow[row0 + r];
#pragma unroll
            for (int j = 0; j < 4; ++j) {
                int col = nbase + wn * 64 + j * 16 + l15;
                out[(size_t)(row0 + r) * 1024 + col] = sv * acc[i][j][r] + bo[col];
            }
        }
    }
}

// --------------------- chunk-parallel linear scan --------------------------
// h_t = (1-dbar_t) h_{t-1} + dbar_t * Bt_t * sA ;  s_t = <h_t, Ct_t>
__global__ __launch_bounds__(256) void scan_kernel(
    const float* __restrict__ dbar, const float* __restrict__ Bt,
    const float* __restrict__ Ct, const float* __restrict__ sA,
    float* __restrict__ s_local, float* __restrict__ pbuf,
    float* __restrict__ Pc, float* __restrict__ Hend)
{
    int tid = threadIdx.x;
    int gid = blockIdx.x * 16 + (tid >> 4);   // 0..NGROUP-1
    int n = tid & 15;
    int b = gid >> 7;         // / NCHUNK
    int c = gid & 127;        // % NCHUNK
    float sAn = sA[n];
    float h = 0.f, p = 1.f;
    int row = b * TLEN + c * CHUNK;
#pragma unroll 4
    for (int t = 0; t < CHUNK; ++t, ++row) {
        float d = dbar[row];
        float btv = Bt[row * 16 + n];
        float ctv = Ct[row * 16 + n];
        float a = 1.f - d;
        h = h * a + d * sAn * btv;
        p *= a;
        float prod = h * ctv;
#pragma unroll
        for (int off = 1; off < 16; off <<= 1) prod += __shfl_xor(prod, off, 16);
        if (n == 0) { s_local[row] = prod; pbuf[row] = p; }
    }
    Hend[gid * 16 + n] = h;
    if (n == 0) Pc[gid] = p;
}

__global__ __launch_bounds__(128) void stitch_kernel(
    const float* __restrict__ Pc, const float* __restrict__ Hend,
    float* __restrict__ h0buf)
{
    int tid = threadIdx.x;           // 128 = 8 batches x 16 n
    int b = tid >> 4, n = tid & 15;
    float h0 = 0.f;
#pragma unroll 8
    for (int c = 0; c < NCHUNK; ++c) {
        int g = b * NCHUNK + c;
        h0buf[g * 16 + n] = h0;
        h0 = Pc[g] * h0 + Hend[g * 16 + n];
    }
}

__global__ __launch_bounds__(256) void fixup_kernel(
    const float* __restrict__ s_local, const float* __restrict__ pbuf,
    const float* __restrict__ h0buf, const float* __restrict__ Ct,
    float* __restrict__ sbuf)
{
    int row = blockIdx.x * 256 + threadIdx.x;
    int b = row >> 12, t = row & 4095;
    int g = b * NCHUNK + (t / CHUNK);
    const float4* h4 = (const float4*)(h0buf + g * 16);
    const float4* c4 = (const float4*)(Ct + (size_t)row * 16);
    float dot = 0.f;
#pragma unroll
    for (int q = 0; q < 4; ++q) {
        float4 hv = h4[q], cv = c4[q];
        dot += hv.x * cv.x + hv.y * cv.y + hv.z * cv.z + hv.w * cv.w;
    }
    sbuf[row] = s_local[row] + pbuf[row] * dot;
}

// ---------------------------------------------------------------------------
extern "C" void kernel_launch(void* const* d_in, const int* in_sizes, int n_in,
                              void* d_out, int out_size, void* d_ws, size_t ws_size,
                              hipStream_t stream)
{
    const float* x  = (const float*)d_in[0];
    const float* Wd = (const float*)d_in[1];
    const float* bd = (const float*)d_in[2];
    const float* Wb = (const float*)d_in[3];
    const float* bb = (const float*)d_in[4];
    const float* Wc = (const float*)d_in[5];
    const float* bc = (const float*)d_in[6];
    const float* Wo = (const float*)d_in[7];
    const float* bo = (const float*)d_in[8];
    const float* A  = (const float*)d_in[9];
    float* out = (float*)d_out;

    char* base = (char*)d_ws;
    size_t off = 0;
    auto alloc = [&](size_t bytes) -> void* {
        void* p = base + off;
        off = (off + bytes + 255) & ~(size_t)255;
        return p;
    };
    __bf16* xb   = (__bf16*)alloc((size_t)M_ROWS * DDIM * 2);  // 67 MB
    __bf16* WdT  = (__bf16*)alloc((size_t)DDIM * DDIM * 2);    // 2 MB
    __bf16* WoT  = (__bf16*)alloc((size_t)DDIM * DDIM * 2);    // 2 MB
    __bf16* Wbc  = (__bf16*)alloc(32 * 1024 * 2);              // 64 KB
    float* sAbuf = (float*)alloc(64);
    float* dbar  = (float*)alloc(M_ROWS * 4);
    float* Bt    = (float*)alloc((size_t)M_ROWS * 16 * 4);     // 2 MB
    float* Ct    = (float*)alloc((size_t)M_ROWS * 16 * 4);     // 2 MB
    float* s_loc = (float*)alloc(M_ROWS * 4);
    float* pbuf  = (float*)alloc(M_ROWS * 4);
    float* sbuf  = (float*)alloc(M_ROWS * 4);
    float* Pc    = (float*)alloc(NGROUP * 4);
    float* Hend  = (float*)alloc(NGROUP * 16 * 4);
    float* h0buf = (float*)alloc(NGROUP * 16 * 4);

    transpose_w_kernel<<<2048, 256, 0, stream>>>(Wd, Wo, WdT, WoT);
    wbc_kernel<<<128, 256, 0, stream>>>(Wb, Wc, Wbc);
    sA_kernel<<<1, 256, 0, stream>>>(A, sAbuf);
    cast_kernel<<<M_ROWS * DDIM / 8 / 256, 256, 0, stream>>>(x, xb);
    (void)hipMemsetAsync(dbar, 0, M_ROWS * 4, stream);
    btct_kernel<<<512, 256, 0, stream>>>(xb, Wbc, bb, bc, Bt, Ct);
    gemm1_kernel<<<512, 512, 0, stream>>>(xb, WdT, bd, dbar);
    scan_kernel<<<NGROUP / 16, 256, 0, stream>>>(dbar, Bt, Ct, sAbuf, s_loc, pbuf, Pc, Hend);
    stitch_kernel<<<1, 128, 0, stream>>>(Pc, Hend, h0buf);
    fixup_kernel<<<M_ROWS / 256, 256, 0, stream>>>(s_loc, pbuf, h0buf, Ct, sbuf);
    gemm2_kernel<<<512, 512, 0, stream>>>(xb, WoT, sbuf, bo, out);
}

// Round 7
// 458.703 us; speedup vs baseline: 1.1931x; 1.0055x over previous
//
#include <hip/hip_runtime.h>
#include <hip/hip_bf16.h>

// ---------------------------------------------------------------------------
// MambaBlock: delta/dbar via bf16 MFMA GEMM1 (fast-softplus+row-mean epilogue),
// Bt/Ct via skinny MFMA GEMM, chunk-parallel linear scan,
// out = diag(s)*(x@Wo)+bo via bf16 MFMA GEMM2 (row-scale epilogue).
// B=8 T=4096 D=1024 N=16, M=B*T=32768.
//
// R3: 256x256-tile 8-wave GEMM core, 4-deep LDS ring + counted vmcnt(8),
//     sigma-swizzled conflict-free LDS subtiles.
// R6: counted lgkmcnt(4)/(0) two-cluster K-tile (gemm1 85us, MfmaUtil 34%).
// R7: dispatch-count reduction 12 -> 6. Kernel sum (~260us) << wall (461us):
//     ~200us is inter-dispatch overhead. (a) mega-prep fuses transpose+wbc+
//     sA+cast+dbar-zero into one kernel (block-range branch, no memset);
//     (b) stitch inlined into fixup (each block recomputes its batch prefix
//     from Pc/Hend). GEMM/btct/scan byte-identical to R6.
// ---------------------------------------------------------------------------

typedef __bf16 bfx4 __attribute__((ext_vector_type(4)));
typedef __bf16 bfx8 __attribute__((ext_vector_type(8)));
typedef float  f32x4 __attribute__((ext_vector_type(4)));

#define M_ROWS 32768
#define DDIM   1024
#define NSTATE 16
#define TLEN   4096
#define BATCH  8
#define CHUNK  32
#define NCHUNK 128   // TLEN / CHUNK
#define NGROUP (BATCH * NCHUNK)   // 1024 scan chains

#define BK     32
#define KT     (DDIM / BK)        // 32 K-tiles
#define TILEE  16384              // elements per ring buffer (A 8192 + B 8192)

// mega-prep block ranges
#define NB_TR   2048
#define NB_WBC  128
#define B_SA    (NB_TR + NB_WBC)            // 2176
#define B_CAST  (B_SA + 1)                  // 2177
#define NB_CAST (M_ROWS * DDIM / 8 / 256)   // 16384
#define B_ZERO  (B_CAST + NB_CAST)          // 18561
#define NB_ZERO (M_ROWS / 256)              // 128
#define NB_PREP (B_ZERO + NB_ZERO)          // 18689

// ---------------- mega-prep: transpose + wbc + sA + cast + dbar-zero -------
__global__ __launch_bounds__(256) void prep_kernel(
    const float* __restrict__ Wd, const float* __restrict__ Wo,
    const float* __restrict__ Wb, const float* __restrict__ Wc,
    const float* __restrict__ A,  const float* __restrict__ x,
    __bf16* __restrict__ WdT, __bf16* __restrict__ WoT,
    __bf16* __restrict__ Wbc, float* __restrict__ sA,
    __bf16* __restrict__ xb,  float* __restrict__ dbar)
{
    __shared__ float tile[32][33];
    const int bid = blockIdx.x;
    const int tid = threadIdx.x;

    if (bid < NB_TR) {
        // tiled transpose fp32 -> bf16 for Wd, Wo (1024x1024)
        const float* src = (bid < 1024) ? Wd : Wo;
        __bf16* dst = (bid < 1024) ? WdT : WoT;
        const int t = bid & 1023;
        const int tr = t >> 5, tc = t & 31;
        const int tx = tid & 31, ty = tid >> 5;  // ty 0..7
#pragma unroll
        for (int i = 0; i < 4; ++i) {
            int r = ty + i * 8;
            tile[r][tx] = src[(size_t)(tr * 32 + r) * 1024 + tc * 32 + tx];
        }
        __syncthreads();
#pragma unroll
        for (int i = 0; i < 4; ++i) {
            int r = ty + i * 8;
            dst[(size_t)(tc * 32 + r) * 1024 + tr * 32 + tx] = (__bf16)tile[tx][r];
        }
    } else if (bid < B_SA) {
        // Wbc: [32][1024] bf16 ; rows 0..15 = Wb^T, rows 16..31 = Wc^T
        int idx = (bid - NB_TR) * 256 + tid;   // 0..32767
        int n2 = idx >> 10, k = idx & 1023;
        float v = (n2 < 16) ? Wb[k * 16 + n2] : Wc[k * 16 + (n2 - 16)];
        Wbc[idx] = (__bf16)v;
    } else if (bid == B_SA) {
        __shared__ float red[256];
        int n = tid & 15, part = tid >> 4;
        float sum = 0.f;
        for (int k = part * 64; k < part * 64 + 64; ++k) sum += A[k * 16 + n];
        red[tid] = sum;
        __syncthreads();
        if (tid < 16) {
            float tot = 0.f;
            for (int p = 0; p < 16; ++p) tot += red[p * 16 + tid];
            sA[tid] = 1.f / (1.f + expf(-tot * (1.f / 1024.f)));
        }
    } else if (bid < B_ZERO) {
        // cast x -> bf16 (pure streaming)
        size_t i = ((size_t)(bid - B_CAST) * 256 + tid) * 8;
        const float4* xg = (const float4*)(x + i);
        float4 v0 = xg[0], v1 = xg[1];
        bfx8 o;
        o[0] = (__bf16)v0.x; o[1] = (__bf16)v0.y; o[2] = (__bf16)v0.z; o[3] = (__bf16)v0.w;
        o[4] = (__bf16)v1.x; o[5] = (__bf16)v1.y; o[6] = (__bf16)v1.z; o[7] = (__bf16)v1.w;
        *(bfx8*)(xb + i) = o;
    } else {
        // zero dbar (replaces hipMemsetAsync)
        int row = (bid - B_ZERO) * 256 + tid;
        dbar[row] = 0.f;
    }
}

// ---------------- Bt/Ct: skinny MFMA GEMM, no LDS --------------------------
__global__ __launch_bounds__(256) void btct_kernel(
    const __bf16* __restrict__ xb, const __bf16* __restrict__ Wbc,
    const float* __restrict__ bb, const float* __restrict__ bc,
    float* __restrict__ Bt, float* __restrict__ Ct)
{
    const int wid = blockIdx.x * 4 + (threadIdx.x >> 6);  // 0..2047
    const int lane = threadIdx.x & 63;
    const int quad = lane >> 4, l15 = lane & 15;
    const int mbase = wid * 16;
    const __bf16* ga = xb + (size_t)(mbase + l15) * 1024 + quad * 8;
    const __bf16* gb = Wbc + (size_t)l15 * 1024 + quad * 8;
    const __bf16* gc = Wbc + (size_t)(16 + l15) * 1024 + quad * 8;
    f32x4 accB = {0.f, 0.f, 0.f, 0.f};
    f32x4 accC = {0.f, 0.f, 0.f, 0.f};
#pragma unroll 4
    for (int k = 0; k < 1024; k += 32) {
        bfx8 a = *(const bfx8*)ga;  ga += 32;
        bfx8 b = *(const bfx8*)gb;  gb += 32;
        bfx8 c = *(const bfx8*)gc;  gc += 32;
        accB = __builtin_amdgcn_mfma_f32_16x16x32_bf16(a, b, accB, 0, 0, 0);
        accC = __builtin_amdgcn_mfma_f32_16x16x32_bf16(a, c, accC, 0, 0, 0);
    }
    // C/D layout: col = lane&15, row = quad*4 + r
#pragma unroll
    for (int r = 0; r < 4; ++r) {
        int row = mbase + quad * 4 + r;
        Bt[row * 16 + l15] = accB[r] + bb[l15];
        Ct[row * 16 + l15] = accC[r] + bc[l15];
    }
}

// ------------------------- 256x256 MFMA GEMM core --------------------------
__device__ __forceinline__ void gload16(const void* g, void* l)
{
    __builtin_amdgcn_global_load_lds((__attribute__((address_space(1))) void*)g,
                                     (__attribute__((address_space(3))) void*)l,
                                     16, 0, 0);
}

// XCD-aware tile swizzle for 512 blocks (128 mtiles x 4 ntiles). Bijective.
__device__ __forceinline__ void tile_swizzle256(int L, int& mtile, int& ntile)
{
    int xcd = L & 7;
    int s = L >> 3;           // 0..63
    mtile = xcd * 16 + (s >> 2);
    ntile = s & 3;
}

// LDS layout per 256x32 bf16 operand tile (16KB = 16 subtiles of 1KB):
//   sigma: kc' = kc ^ (((row&15)>>1)&3) within each 64B row (within-line
//   permutation only -> staging groups stay inside one 64B global line).
// Fragment read: any 8 consecutive lanes hit 8 distinct 16B slots -> 0 confl.
// Ring: 4 buffers x 32KB = 128KB; stage t+3 while computing t; vmcnt(8)/tile.
__device__ __forceinline__ void stage_tile(const __bf16* pA0, const __bf16* pA1,
                                           const __bf16* pB0, const __bf16* pB1,
                                           __bf16* lbase, int tid, int t)
{
    const size_t ko = (size_t)t * BK;
    __bf16* ba = lbase;
    __bf16* bb2 = lbase + 8192;
    gload16(pA0 + ko, ba + tid * 8);
    gload16(pA1 + ko, ba + 4096 + tid * 8);
    gload16(pB0 + ko, bb2 + tid * 8);
    gload16(pB1 + ko, bb2 + 4096 + tid * 8);
}

__device__ __forceinline__ void gemm_core256(const __bf16* __restrict__ Abuf,
                                             const __bf16* __restrict__ Bbuf,
                                             __bf16* lds,
                                             int mbase, int nbase,
                                             f32x4 acc[8][4])
{
    const int tid = threadIdx.x;
    const int lane = tid & 63;
    const int w = tid >> 6;
    const int quad = lane >> 4, l15 = lane & 15;
    const int wm = w >> 2, wn = w & 3;        // 2 x 4 wave grid

    // staging source addressing (per thread)
    const int row0 = ((tid >> 6) << 4) + ((tid >> 2) & 15);
    const int kc   = (tid & 3) ^ ((tid >> 3) & 3);
    const __bf16* pA0 = Abuf + (size_t)(mbase + row0) * DDIM + kc * 8;
    const __bf16* pA1 = pA0 + (size_t)128 * DDIM;
    const __bf16* pB0 = Bbuf + (size_t)(nbase + row0) * DDIM + kc * 8;
    const __bf16* pB1 = pB0 + (size_t)128 * DDIM;

    // fragment read offsets (sigma-swizzled slot within subtile)
    const int vsw  = l15 * 4 + (quad ^ ((l15 >> 1) & 3));
    const int aoff = wm * 8 * 512 + vsw * 8;
    const int boff = wn * 4 * 512 + vsw * 8;

    // prologue: stage tiles 0,1,2 (12 loads in flight)
    stage_tile(pA0, pA1, pB0, pB1, lds + 0 * TILEE, tid, 0);
    stage_tile(pA0, pA1, pB0, pB1, lds + 1 * TILEE, tid, 1);
    stage_tile(pA0, pA1, pB0, pB1, lds + 2 * TILEE, tid, 2);

#pragma unroll 1
    for (int t = 0; t < KT; ++t) {
        // tile t's 4 loads are the oldest outstanding; up to 8 newer remain
        if (t < KT - 2)       asm volatile("s_waitcnt vmcnt(8)" ::: "memory");
        else if (t == KT - 2) asm volatile("s_waitcnt vmcnt(4)" ::: "memory");
        else                  asm volatile("s_waitcnt vmcnt(0)" ::: "memory");
        __builtin_amdgcn_s_barrier();
        __builtin_amdgcn_sched_barrier(0);

        const __bf16* Al = lds + (t & 3) * TILEE;
        const __bf16* Bl = Al + 8192;
        const size_t ko3 = (size_t)(t + 3) * BK;
        __bf16* lb3 = lds + ((t + 3) & 3) * TILEE;

        // issue all 12 ds_reads (order: bfr0-3, af0-3, ag0-3) with staging
        // interleaved; counted lgkm waits split the MFMA into two clusters
        // so ag-reads + B-half staging ride under the first cluster.
        bfx8 bfr[4], af[4], ag[4];
#pragma unroll
        for (int j = 0; j < 4; ++j) bfr[j] = *(const bfx8*)(Bl + boff + j * 512);
#pragma unroll
        for (int i = 0; i < 4; ++i) af[i]  = *(const bfx8*)(Al + aoff + i * 512);
        if (t < KT - 3) {
            gload16(pA0 + ko3, lb3 + tid * 8);
            gload16(pA1 + ko3, lb3 + 4096 + tid * 8);
        }
#pragma unroll
        for (int i = 0; i < 4; ++i) ag[i] = *(const bfx8*)(Al + aoff + (4 + i) * 512);
        if (t < KT - 3) {
            gload16(pB0 + ko3, lb3 + 8192 + tid * 8);
            gload16(pB1 + ko3, lb3 + 8192 + 4096 + tid * 8);
        }
        // first 8 ds_reads (bfr, af) complete; ag still in flight
        asm volatile("s_waitcnt lgkmcnt(4)" ::: "memory");
        __builtin_amdgcn_sched_barrier(0);
        __builtin_amdgcn_s_setprio(1);
#pragma unroll
        for (int i = 0; i < 4; ++i)
#pragma unroll
            for (int j = 0; j < 4; ++j)
                acc[i][j] = __builtin_amdgcn_mfma_f32_16x16x32_bf16(
                    af[i], bfr[j], acc[i][j], 0, 0, 0);
        __builtin_amdgcn_s_setprio(0);
        asm volatile("s_waitcnt lgkmcnt(0)" ::: "memory");
        __builtin_amdgcn_sched_barrier(0);
        __builtin_amdgcn_s_setprio(1);
#pragma unroll
        for (int i = 0; i < 4; ++i)
#pragma unroll
            for (int j = 0; j < 4; ++j)
                acc[4 + i][j] = __builtin_amdgcn_mfma_f32_16x16x32_bf16(
                    ag[i], bfr[j], acc[4 + i][j], 0, 0, 0);
        __builtin_amdgcn_s_setprio(0);
    }
}

// GEMM1: z = x@Wd + bd ; dbar[row] += mean_cols softplus(z)
__global__ __launch_bounds__(512, 2) void gemm1_kernel(
    const __bf16* __restrict__ xb, const __bf16* __restrict__ WdT,
    const float* __restrict__ bd, float* __restrict__ dbar)
{
    __shared__ __bf16 lds[4 * TILEE];   // 128 KB
    f32x4 acc[8][4];
    f32x4 z4 = {0.f, 0.f, 0.f, 0.f};
#pragma unroll
    for (int i = 0; i < 8; ++i)
#pragma unroll
        for (int j = 0; j < 4; ++j) acc[i][j] = z4;

    int mtile, ntile;
    tile_swizzle256(blockIdx.x, mtile, ntile);
    const int mbase = mtile * 256;
    const int nbase = ntile * 256;
    gemm_core256(xb, WdT, lds, mbase, nbase, acc);

    const int lane = threadIdx.x & 63;
    const int w = threadIdx.x >> 6;
    const int quad = lane >> 4, l15 = lane & 15;
    const int wm = w >> 2, wn = w & 3;
    const float invD = 1.0f / 1024.0f;
#pragma unroll
    for (int i = 0; i < 8; ++i) {
#pragma unroll
        for (int r = 0; r < 4; ++r) {
            float sp = 0.f;
#pragma unroll
            for (int j = 0; j < 4; ++j) {
                int col = nbase + wn * 64 + j * 16 + l15;
                float z = acc[i][j][r] + bd[col];
                sp += fmaxf(z, 0.f) + __logf(1.f + __expf(-fabsf(z)));
            }
#pragma unroll
            for (int off = 1; off < 16; off <<= 1) sp += __shfl_xor(sp, off, 16);
            if (l15 == 0) {
                int row = mbase + wm * 128 + i * 16 + quad * 4 + r;
                atomicAdd(&dbar[row], sp * invD);
            }
        }
    }
}

// GEMM2: out[row][col] = s[row]*(x@Wo)[row][col] + bo[col]
__global__ __launch_bounds__(512, 2) void gemm2_kernel(
    const __bf16* __restrict__ xb, const __bf16* __restrict__ WoT,
    const float* __restrict__ srow, const float* __restrict__ bo,
    float* __restrict__ out)
{
    __shared__ __bf16 lds[4 * TILEE];   // 128 KB
    f32x4 acc[8][4];
    f32x4 z4 = {0.f, 0.f, 0.f, 0.f};
#pragma unroll
    for (int i = 0; i < 8; ++i)
#pragma unroll
        for (int j = 0; j < 4; ++j) acc[i][j] = z4;

    int mtile, ntile;
    tile_swizzle256(blockIdx.x, mtile, ntile);
    const int mbase = mtile * 256;
    const int nbase = ntile * 256;
    gemm_core256(xb, WoT, lds, mbase, nbase, acc);

    const int lane = threadIdx.x & 63;
    const int w = threadIdx.x >> 6;
    const int quad = lane >> 4, l15 = lane & 15;
    const int wm = w >> 2, wn = w & 3;
#pragma unroll
    for (int i = 0; i < 8; ++i) {
        int row0 = mbase + wm * 128 + i * 16 + quad * 4;
#pragma unroll
        for (int r = 0; r < 4; ++r) {
            float sv = srow[row0 + r];
#pragma unroll
            for (int j = 0; j < 4; ++j) {
                int col = nbase + wn * 64 + j * 16 + l15;
                out[(size_t)(row0 + r) * 1024 + col] = sv * acc[i][j][r] + bo[col];
            }
        }
    }
}

// --------------------- chunk-parallel linear scan --------------------------
// h_t = (1-dbar_t) h_{t-1} + dbar_t * Bt_t * sA ;  s_t = <h_t, Ct_t>
__global__ __launch_bounds__(256) void scan_kernel(
    const float* __restrict__ dbar, const float* __restrict__ Bt,
    const float* __restrict__ Ct, const float* __restrict__ sA,
    float* __restrict__ s_local, float* __restrict__ pbuf,
    float* __restrict__ Pc, float* __restrict__ Hend)
{
    int tid = threadIdx.x;
    int gid = blockIdx.x * 16 + (tid >> 4);   // 0..NGROUP-1
    int n = tid & 15;
    int b = gid >> 7;         // / NCHUNK
    int c = gid & 127;        // % NCHUNK
    float sAn = sA[n];
    float h = 0.f, p = 1.f;
    int row = b * TLEN + c * CHUNK;
#pragma unroll 4
    for (int t = 0; t < CHUNK; ++t, ++row) {
        float d = dbar[row];
        float btv = Bt[row * 16 + n];
        float ctv = Ct[row * 16 + n];
        float a = 1.f - d;
        h = h * a + d * sAn * btv;
        p *= a;
        float prod = h * ctv;
#pragma unroll
        for (int off = 1; off < 16; off <<= 1) prod += __shfl_xor(prod, off, 16);
        if (n == 0) { s_local[row] = prod; pbuf[row] = p; }
    }
    Hend[gid * 16 + n] = h;
    if (n == 0) Pc[gid] = p;
}

// fixup with inline stitch: each block (256 rows = 8 chunks, one batch
// segment) recomputes the chunk-prefix h0 for its batch from Pc/Hend
// (loads are h0-independent -> pipelined by unroll), then applies
// s = s_local + pbuf * <h0, Ct>.
__global__ __launch_bounds__(256) void fixup_kernel(
    const float* __restrict__ s_local, const float* __restrict__ pbuf,
    const float* __restrict__ Pc, const float* __restrict__ Hend,
    const float* __restrict__ Ct, float* __restrict__ sbuf)
{
    __shared__ float H0_s[8][16];
    const int tid = threadIdx.x;
    const int row0 = blockIdx.x * 256;
    const int b = row0 >> 12;                 // batch
    const int cstart = (row0 & 4095) >> 5;    // first chunk of this block
    if (tid < 16) {
        float h0 = 0.f;
        const int gbase = b * NCHUNK;
        const int cend = cstart + 8;
#pragma unroll 8
        for (int c = 0; c < cend; ++c) {
            if (c >= cstart) H0_s[c - cstart][tid] = h0;
            h0 = Pc[gbase + c] * h0 + Hend[(gbase + c) * 16 + tid];
        }
    }
    __syncthreads();
    const int row = row0 + tid;
    const int lc = (tid >> 5);                // local chunk 0..7
    const float4* h4 = (const float4*)(&H0_s[lc][0]);
    const float4* c4 = (const float4*)(Ct + (size_t)row * 16);
    float dot = 0.f;
#pragma unroll
    for (int q = 0; q < 4; ++q) {
        float4 hv = h4[q], cv = c4[q];
        dot += hv.x * cv.x + hv.y * cv.y + hv.z * cv.z + hv.w * cv.w;
    }
    sbuf[row] = s_local[row] + pbuf[row] * dot;
}

// ---------------------------------------------------------------------------
extern "C" void kernel_launch(void* const* d_in, const int* in_sizes, int n_in,
                              void* d_out, int out_size, void* d_ws, size_t ws_size,
                              hipStream_t stream)
{
    const float* x  = (const float*)d_in[0];
    const float* Wd = (const float*)d_in[1];
    const float* bd = (const float*)d_in[2];
    const float* Wb = (const float*)d_in[3];
    const float* bb = (const float*)d_in[4];
    const float* Wc = (const float*)d_in[5];
    const float* bc = (const float*)d_in[6];
    const float* Wo = (const float*)d_in[7];
    const float* bo = (const float*)d_in[8];
    const float* A  = (const float*)d_in[9];
    float* out = (float*)d_out;

    char* base = (char*)d_ws;
    size_t off = 0;
    auto alloc = [&](size_t bytes) -> void* {
        void* p = base + off;
        off = (off + bytes + 255) & ~(size_t)255;
        return p;
    };
    __bf16* xb   = (__bf16*)alloc((size_t)M_ROWS * DDIM * 2);  // 67 MB
    __bf16* WdT  = (__bf16*)alloc((size_t)DDIM * DDIM * 2);    // 2 MB
    __bf16* WoT  = (__bf16*)alloc((size_t)DDIM * DDIM * 2);    // 2 MB
    __bf16* Wbc  = (__bf16*)alloc(32 * 1024 * 2);              // 64 KB
    float* sAbuf = (float*)alloc(64);
    float* dbar  = (float*)alloc(M_ROWS * 4);
    float* Bt    = (float*)alloc((size_t)M_ROWS * 16 * 4);     // 2 MB
    float* Ct    = (float*)alloc((size_t)M_ROWS * 16 * 4);     // 2 MB
    float* s_loc = (float*)alloc(M_ROWS * 4);
    float* pbuf  = (float*)alloc(M_ROWS * 4);
    float* sbuf  = (float*)alloc(M_ROWS * 4);
    float* Pc    = (float*)alloc(NGROUP * 4);
    float* Hend  = (float*)alloc(NGROUP * 16 * 4);

    prep_kernel<<<NB_PREP, 256, 0, stream>>>(Wd, Wo, Wb, Wc, A, x,
                                             WdT, WoT, Wbc, sAbuf, xb, dbar);
    btct_kernel<<<512, 256, 0, stream>>>(xb, Wbc, bb, bc, Bt, Ct);
    gemm1_kernel<<<512, 512, 0, stream>>>(xb, WdT, bd, dbar);
    scan_kernel<<<NGROUP / 16, 256, 0, stream>>>(dbar, Bt, Ct, sAbuf, s_loc, pbuf, Pc, Hend);
    fixup_kernel<<<M_ROWS / 256, 256, 0, stream>>>(s_loc, pbuf, Pc, Hend, Ct, sbuf);
    gemm2_kernel<<<512, 512, 0, stream>>>(xb, WoT, sbuf, bo, out);
}